// Round 1
// baseline (201.120 us; speedup 1.0000x reference)
//
#include <hip/hip_runtime.h>

// MemoryProjection: x_t = A x_{t-1} + in_t * Bd, out = all states.
// Chunked formulation: out[j*64+tau] = A^(tau+1) x0_j + sum_{k<=tau} (A^(tau-k) Bd) in[j*64+k]
// => one fp16 MFMA GEMM: C[m=(j,q)][nn=(tau,n)] = R16[m][:] . W16[nn][:], K=256
//    R16 = [in(64) | x0h(64) | x0h(64) | x0l(64)], W16 = [Kmat | Ph | Pl | Ph]
// All products fp16*fp16 -> fp32 exact; x0 exact fp32 from a 32-step scan -> error ~1e-4.
// ws usage ~15.2 MB (G 96KB, P 1MB, Kv 16KB, c 4MB, W16 2MB, R16 8MB).

typedef _Float16 f16;
typedef __attribute__((ext_vector_type(8))) _Float16 f16x8;
typedef __attribute__((ext_vector_type(4))) float f32x4;

// ---------------- K1: G[s] = A^(2^s), s=0..5; Kv[j] = A^j Bd, j=0..63 ----------------
__global__ __launch_bounds__(1024) void k1_powers(
    const float* __restrict__ A, const float* __restrict__ Bm,
    float* __restrict__ G, float* __restrict__ Kv)
{
  __shared__ float LA[64][68];
  __shared__ float xv[64];
  __shared__ float xn[64];
  int t = threadIdx.x;
  for (int idx = t; idx < 4096; idx += 1024) {
    float v = A[idx];
    G[idx] = v;
    LA[idx >> 6][idx & 63] = v;
  }
  __syncthreads();
  int n = t >> 4, m0 = (t & 15) * 4;
  // 5 sequential squarings: LA <- LA @ LA, store G[s]
  for (int s = 1; s <= 5; ++s) {
    float a0 = 0.f, a1 = 0.f, a2 = 0.f, a3 = 0.f;
    #pragma unroll 8
    for (int k = 0; k < 64; ++k) {
      float a = LA[n][k];
      a0 += a * LA[k][m0 + 0];
      a1 += a * LA[k][m0 + 1];
      a2 += a * LA[k][m0 + 2];
      a3 += a * LA[k][m0 + 3];
    }
    __syncthreads();
    LA[n][m0 + 0] = a0; LA[n][m0 + 1] = a1;
    LA[n][m0 + 2] = a2; LA[n][m0 + 3] = a3;
    float* Gs = G + s * 4096;
    Gs[n * 64 + m0 + 0] = a0; Gs[n * 64 + m0 + 1] = a1;
    Gs[n * 64 + m0 + 2] = a2; Gs[n * 64 + m0 + 3] = a3;
    __syncthreads();
  }
  // reload plain A for the Kv matvec chain
  for (int idx = t; idx < 1024 * 4; idx += 1024)
    LA[idx >> 6][idx & 63] = A[idx];
  if (t < 64) { float b = Bm[t]; xv[t] = b; Kv[t] = b; }
  __syncthreads();
  int seg = t & 15;
  float ar0 = LA[n][seg * 4 + 0], ar1 = LA[n][seg * 4 + 1];
  float ar2 = LA[n][seg * 4 + 2], ar3 = LA[n][seg * 4 + 3];
  for (int j = 1; j < 64; ++j) {
    float p = ar0 * xv[seg * 4 + 0] + ar1 * xv[seg * 4 + 1]
            + ar2 * xv[seg * 4 + 2] + ar3 * xv[seg * 4 + 3];
    p += __shfl_xor(p, 1, 16);
    p += __shfl_xor(p, 2, 16);
    p += __shfl_xor(p, 4, 16);
    p += __shfl_xor(p, 8, 16);
    __syncthreads();
    if (seg == 0) xn[n] = p;
    __syncthreads();
    if (t < 64) { xv[t] = xn[t]; Kv[j * 64 + t] = xn[t]; }
    __syncthreads();
  }
}

// ---------------- K2: P[tau] = A^(tau+1) (binary product of G); build W16 rows ----------------
__global__ __launch_bounds__(256) void k2_pw(
    const float* __restrict__ G, const float* __restrict__ Kv,
    float* __restrict__ P, f16* __restrict__ W16)
{
  __shared__ float Lacc[64][68];
  __shared__ float Lb[64][68];
  int tau = blockIdx.x;
  int t = threadIdx.x;
  int e = tau + 1;
  int facs[8]; int nf = 0;
  if (e == 64) { facs[0] = 5; facs[1] = 5; nf = 2; }
  else { for (int i = 0; i <= 5; ++i) if (e & (1 << i)) facs[nf++] = i; }
  const float* F0 = G + facs[0] * 4096;
  for (int idx = t; idx < 4096; idx += 256) Lacc[idx >> 6][idx & 63] = F0[idx];
  __syncthreads();
  int n = t >> 2, ms = (t & 3) * 16;
  for (int fi = 1; fi < nf; ++fi) {
    const float* Ff = G + facs[fi] * 4096;
    for (int idx = t; idx < 4096; idx += 256) Lb[idx >> 6][idx & 63] = Ff[idx];
    __syncthreads();
    float accv[16];
    #pragma unroll
    for (int i = 0; i < 16; ++i) accv[i] = 0.f;
    #pragma unroll 4
    for (int k = 0; k < 64; ++k) {
      float a = Lacc[n][k];
      #pragma unroll
      for (int i = 0; i < 16; ++i) accv[i] += a * Lb[k][ms + i];
    }
    __syncthreads();
    #pragma unroll
    for (int i = 0; i < 16; ++i) Lacc[n][ms + i] = accv[i];
    __syncthreads();
  }
  float* Pt = P + tau * 4096;
  for (int idx = t; idx < 4096; idx += 256) Pt[idx] = Lacc[idx >> 6][idx & 63];
  // W row: [Kmat(64) | Ph(64) | Pl(64) | Ph(64)]
  int wn = t & 63, kq = t >> 6;
  f16* wrow = W16 + ((size_t)(tau * 64 + wn)) * 256 + kq * 64;
  if (kq == 0) {
    for (int k = 0; k < 64; ++k)
      wrow[k] = (f16)((k <= tau) ? Kv[(tau - k) * 64 + wn] : 0.0f);
  } else if (kq == 2) {
    for (int m = 0; m < 64; ++m) {
      float p = Lacc[wn][m];
      f16 h = (f16)p;
      wrow[m] = (f16)(p - (float)h);
    }
  } else {
    for (int m = 0; m < 64; ++m) wrow[m] = (f16)Lacc[wn][m];
  }
}

// ---------------- K3: per-chunk: R16 in-part (transpose) + c_j = sum_k Kv[63-k] in[k] ----------------
__global__ __launch_bounds__(256) void k3_chunk(
    const float* __restrict__ inp, const float* __restrict__ Kv,
    float* __restrict__ c, f16* __restrict__ R16)
{
  __shared__ float tile[64][132];   // [k][q]
  __shared__ float kvs[64][65];     // kvs[k][n] = Kv[63-k][n]
  int j = blockIdx.x >> 2, qb = (blockIdx.x & 3) * 128;
  int t = threadIdx.x;
  {
    int k = t >> 2, sg = (t & 3) * 32;
    const float* src = inp + j * 32768 + k * 512 + qb + sg;
    #pragma unroll
    for (int i = 0; i < 32; i += 4)
      *(f32x4*)(&tile[k][sg + i]) = *(const f32x4*)(src + i);
    for (int idx = t; idx < 4096; idx += 256) {
      int kk = idx >> 6, nn2 = idx & 63;
      kvs[kk][nn2] = Kv[(63 - kk) * 64 + nn2];
    }
  }
  __syncthreads();
  // R16 in-part: R16[(j*512+q)][k] = fp16(in[j*64+k][q])
  {
    int q = t >> 1, kh = (t & 1) * 32;
    f16* dst = R16 + ((size_t)(j * 512 + qb + q)) * 256 + kh;
    #pragma unroll
    for (int kk = 0; kk < 32; ++kk)
      dst[kk] = (f16)tile[kh + kk][q];
  }
  // c[j][q][n]
  {
    int n = t & 63, qq = t >> 6;
    float acc[32];
    #pragma unroll
    for (int i = 0; i < 32; ++i) acc[i] = 0.f;
    #pragma unroll 2
    for (int k = 0; k < 64; ++k) {
      float w = kvs[k][n];
      #pragma unroll
      for (int i4 = 0; i4 < 8; ++i4) {
        f32x4 v = *(const f32x4*)(&tile[k][qq * 32 + i4 * 4]);
        acc[i4 * 4 + 0] += w * v.x;
        acc[i4 * 4 + 1] += w * v.y;
        acc[i4 * 4 + 2] += w * v.z;
        acc[i4 * 4 + 3] += w * v.w;
      }
    }
    float* cb = c + (size_t)j * 32768 + (size_t)(qb + qq * 32) * 64 + n;
    #pragma unroll
    for (int i = 0; i < 32; ++i) cb[i * 64] = acc[i];
  }
}

// ---------------- K4: 32-step chunk-state scan (fp32, exact); writes x0 h/l into R16 ----------------
__global__ __launch_bounds__(256) void k4_scan(
    const float* __restrict__ P, const float* __restrict__ c,
    f16* __restrict__ R16)
{
  __shared__ float x[4][64];
  int t = threadIdx.x;
  int col = t >> 6, n = t & 63;   // one wave per column
  int q = blockIdx.x * 4 + col;
  float ar[64];
  const float* ACr = P + 63 * 4096 + n * 64;   // A^64 row n
  #pragma unroll
  for (int m = 0; m < 64; m += 4) {
    f32x4 v = *(const f32x4*)(ACr + m);
    ar[m] = v.x; ar[m + 1] = v.y; ar[m + 2] = v.z; ar[m + 3] = v.w;
  }
  x[col][n] = 0.f;
  __syncthreads();
  for (int j = 0; j < 32; ++j) {
    float xval = x[col][n];           // x0_j (state before chunk j)
    f16 h = (f16)xval;
    f16 l = (f16)(xval - (float)h);
    f16* row = R16 + ((size_t)(j * 512 + q)) * 256;
    row[64 + n] = h; row[128 + n] = h; row[192 + n] = l;
    float acc = c[(size_t)j * 32768 + (size_t)q * 64 + n];
    #pragma unroll
    for (int m = 0; m < 64; ++m) acc += ar[m] * x[col][m];
    __syncthreads();
    x[col][n] = acc;
    __syncthreads();
  }
}

// ---------------- K5: the big GEMM: C[16384 x 4096] = R16[16384 x 256] @ W16^T ----------------
__global__ __launch_bounds__(256) void k5_gemm(
    const f16* __restrict__ R16, const f16* __restrict__ W16,
    float* __restrict__ out)
{
  __shared__ f16 Asm[128][72];
  __shared__ f16 Bsm[128][72];
  int wg = blockIdx.x;
  int swz = (wg & 7) * 512 + (wg >> 3);     // XCD-contiguous mt ranges
  int mt = swz >> 5, nt = swz & 31;
  int t = threadIdx.x, wave = t >> 6, lane = t & 63;
  int wr = wave >> 1, wc = wave & 1;
  int kg = lane >> 4, fr = lane & 15;
  f32x4 acc[4][4] = {};
  for (int ks = 0; ks < 4; ++ks) {
    #pragma unroll
    for (int ii = 0; ii < 4; ++ii) {
      int s = t + ii * 256;
      int row = s >> 3, sg = (s & 7) * 8;
      *(f16x8*)(&Asm[row][sg]) =
        *(const f16x8*)(R16 + ((size_t)(mt * 128 + row)) * 256 + ks * 64 + sg);
      *(f16x8*)(&Bsm[row][sg]) =
        *(const f16x8*)(W16 + ((size_t)(nt * 128 + row)) * 256 + ks * 64 + sg);
    }
    __syncthreads();
    #pragma unroll
    for (int kk = 0; kk < 2; ++kk) {
      f16x8 af[4], bf[4];
      #pragma unroll
      for (int i = 0; i < 4; ++i) {
        af[i] = *(const f16x8*)(&Asm[wr * 64 + i * 16 + fr][kk * 32 + kg * 8]);
        bf[i] = *(const f16x8*)(&Bsm[wc * 64 + i * 16 + fr][kk * 32 + kg * 8]);
      }
      #pragma unroll
      for (int mi = 0; mi < 4; ++mi)
        #pragma unroll
        for (int ni = 0; ni < 4; ++ni)
          acc[mi][ni] = __builtin_amdgcn_mfma_f32_16x16x32_f16(
              af[mi], bf[ni], acc[mi][ni], 0, 0, 0);
    }
    __syncthreads();
  }
  // epilogue: C row m=(j,q), col nn=(tau,n) -> out[j*64+tau][q][n]
  #pragma unroll
  for (int mi = 0; mi < 4; ++mi) {
    #pragma unroll
    for (int ni = 0; ni < 4; ++ni) {
      int nn = nt * 128 + wc * 64 + ni * 16 + fr;
      int tau = nn >> 6, n = nn & 63;
      #pragma unroll
      for (int r = 0; r < 4; ++r) {
        int m = mt * 128 + wr * 64 + mi * 16 + kg * 4 + r;
        int j = m >> 9, q = m & 511;
        out[(size_t)j * 2097152 + (size_t)tau * 32768 + (size_t)q * 64 + n] =
            acc[mi][ni][r];
      }
    }
  }
}

extern "C" void kernel_launch(void* const* d_in, const int* in_sizes, int n_in,
                              void* d_out, int out_size, void* d_ws, size_t ws_size,
                              hipStream_t stream)
{
  (void)in_sizes; (void)n_in; (void)out_size; (void)ws_size;
  const float* inp = (const float*)d_in[0];   // (2048, 8, 64) fp32
  const float* A   = (const float*)d_in[1];   // (64, 64) fp32
  const float* Bm  = (const float*)d_in[2];   // (64, 1) fp32
  float* out = (float*)d_out;                 // (2048, 8, 64, 64) fp32

  float* ws = (float*)d_ws;
  float* G  = ws;                             // 6*4096 floats
  float* P  = ws + 24576;                     // 64*4096 floats
  float* Kv = ws + 286720;                    // 64*64 floats
  float* c  = ws + 290816;                    // 32*512*64 floats
  f16*  W16 = (f16*)(ws + 1339392);           // 4096*256 halves (2 MB)
  f16*  R16 = (f16*)((char*)d_ws + 7454720);  // 16384*256 halves (8 MB)
  // total ws: ~15.2 MB

  hipLaunchKernelGGL(k1_powers, dim3(1),    dim3(1024), 0, stream, A, Bm, G, Kv);
  hipLaunchKernelGGL(k2_pw,     dim3(64),   dim3(256),  0, stream, G, Kv, P, W16);
  hipLaunchKernelGGL(k3_chunk,  dim3(128),  dim3(256),  0, stream, inp, Kv, c, R16);
  hipLaunchKernelGGL(k4_scan,   dim3(128),  dim3(256),  0, stream, P, c, R16);
  hipLaunchKernelGGL(k5_gemm,   dim3(4096), dim3(256),  0, stream, R16, W16, out);
}

// Round 2
// 165.141 us; speedup vs baseline: 1.2179x; 1.2179x over previous
//
#include <hip/hip_runtime.h>

// MemoryProjection: x_t = A x_{t-1} + in_t * Bd, out = all states (2048,8,64,64) fp32.
// Chunked: out[j*64+tau] = A^(tau+1) x0_j + sum_{k<=tau} (A^(tau-k) Bd) in[j*64+k]
// => one fp16 MFMA GEMM: C[m=(j,q)][nn=(tau,n)] = R16[m][:] . W16[nn][:], K=256
//    R16 = [in(64) | x0h(64) | x0h(64) | x0l(64)], W16 = [Kmat | Ph | Pl | Ph]
// k12: P[tau]=A^(tau+1) via A^(8a)*A^b (<=14 seq 64^3 matmuls, redundant per block); Kv[j]=P[j-1]Bd
// k3:  blocks 0..127 input transpose->R16 + c_j = sum Kv[63-k] in[k]; blocks 128..191 build W16
// k4:  32-step chunk-state scan, state in wave lanes, shfl matvec, no block syncs
// k5:  128x128 MFMA GEMM, epilogue staged through LDS for contiguous 32KB writes

typedef _Float16 f16;
typedef __attribute__((ext_vector_type(8))) _Float16 f16x8;
typedef __attribute__((ext_vector_type(4))) float f32x4;

// ---------------- K12: P[tau] = A^(tau+1); Kv ----------------
__global__ __launch_bounds__(1024) void k12_pow(
    const float* __restrict__ A, const float* __restrict__ Bm,
    float* __restrict__ P, float* __restrict__ Kv)
{
  __shared__ float L1[64][68];
  __shared__ float Cur[64][68];
  __shared__ float Nxt[64][68];
  __shared__ float LbS[64][68];
  __shared__ float L8S[64][68];
  int tau = blockIdx.x;
  int e = tau + 1;
  int a = e >> 3, b = e & 7;
  int t = threadIdx.x;
  int n = t >> 4, m0 = (t & 15) * 4;

  for (int idx = t; idx < 4096; idx += 1024) {
    float v = A[idx];
    L1[idx >> 6][idx & 63] = v;
    Cur[idx >> 6][idx & 63] = v;
  }
  __syncthreads();

  auto mm = [&](float (*s1)[68], float (*s2)[68], float (*d)[68]) {
    float a0 = 0.f, a1 = 0.f, a2 = 0.f, a3 = 0.f;
    #pragma unroll 8
    for (int k = 0; k < 64; ++k) {
      float av = s1[n][k];
      f32x4 bv = *(const f32x4*)(&s2[k][m0]);
      a0 += av * bv.x; a1 += av * bv.y; a2 += av * bv.z; a3 += av * bv.w;
    }
    d[n][m0 + 0] = a0; d[n][m0 + 1] = a1;
    d[n][m0 + 2] = a2; d[n][m0 + 3] = a3;
    __syncthreads();
  };
  auto cpy = [&](float (*s)[68], float (*d)[68]) {
    for (int idx = t; idx < 4096; idx += 1024)
      d[idx >> 6][idx & 63] = s[idx >> 6][idx & 63];
    __syncthreads();
  };

  float (*cur)[68] = Cur, (*oth)[68] = Nxt;
  if (b == 1) cpy(cur, LbS);
  int loMax = (a >= 1) ? 8 : b;
  for (int i = 2; i <= loMax; ++i) {
    mm(cur, L1, oth);
    { float (*tmp)[68] = cur; cur = oth; oth = tmp; }
    if (i == b) cpy(cur, LbS);
    if (i == 8) cpy(cur, L8S);
  }

  float (*res)[68];
  if (a == 0) {
    res = LbS;
  } else {
    float (*d0)[68] = Cur, (*d1)[68] = Nxt;
    float (*h)[68] = L8S;
    for (int a2 = 2; a2 <= a; ++a2) {
      mm(h, L8S, d0);
      h = d0;
      { float (*tmp)[68] = d0; d0 = d1; d1 = tmp; }
    }
    if (b == 0) { res = h; }
    else        { mm(h, LbS, d0); res = d0; }
  }

  for (int idx = t; idx < 4096; idx += 1024)
    P[tau * 4096 + idx] = res[idx >> 6][idx & 63];
  if (t < 64) {
    float s = 0.f;
    #pragma unroll 8
    for (int m = 0; m < 64; ++m) s += res[t][m] * Bm[m];
    if (tau < 63) Kv[(tau + 1) * 64 + t] = s;
    else          Kv[t] = Bm[t];
  }
}

// ---------------- K3: blocks 0..127 transpose+c; blocks 128..191 W16 ----------------
__global__ __launch_bounds__(256) void k3_chunk(
    const float* __restrict__ inp, const float* __restrict__ Kv,
    const float* __restrict__ P,
    float* __restrict__ c, f16* __restrict__ R16, f16* __restrict__ W16)
{
  __shared__ __align__(16) char sm3[64 * 132 * 4 + 64 * 65 * 4];
  int t = threadIdx.x;
  if (blockIdx.x < 128) {
    float (*tile)[132] = (float (*)[132])sm3;                  // [k][q]
    float (*kvs)[65]   = (float (*)[65])(sm3 + 64 * 132 * 4);  // kvs[k][n]=Kv[63-k][n]
    int j = blockIdx.x >> 2, qb = (blockIdx.x & 3) * 128;
    {
      int k = t >> 2, sg = (t & 3) * 32;
      const float* src = inp + j * 32768 + k * 512 + qb + sg;
      #pragma unroll
      for (int i = 0; i < 32; i += 4)
        *(f32x4*)(&tile[k][sg + i]) = *(const f32x4*)(src + i);
      for (int idx = t; idx < 4096; idx += 256) {
        int kk = idx >> 6, nn2 = idx & 63;
        kvs[kk][nn2] = Kv[(63 - kk) * 64 + nn2];
      }
    }
    __syncthreads();
    {
      int q = t >> 1, kh = (t & 1) * 32;
      f16* dst = R16 + ((size_t)(j * 512 + qb + q)) * 256 + kh;
      #pragma unroll
      for (int kk = 0; kk < 32; ++kk)
        dst[kk] = (f16)tile[kh + kk][q];
    }
    {
      int n = t & 63, qq = t >> 6;
      float acc[32];
      #pragma unroll
      for (int i = 0; i < 32; ++i) acc[i] = 0.f;
      #pragma unroll 2
      for (int k = 0; k < 64; ++k) {
        float w = kvs[k][n];
        #pragma unroll
        for (int i4 = 0; i4 < 8; ++i4) {
          f32x4 v = *(const f32x4*)(&tile[k][qq * 32 + i4 * 4]);
          acc[i4 * 4 + 0] += w * v.x;
          acc[i4 * 4 + 1] += w * v.y;
          acc[i4 * 4 + 2] += w * v.z;
          acc[i4 * 4 + 3] += w * v.w;
        }
      }
      float* cb = c + (size_t)j * 32768 + (size_t)(qb + qq * 32) * 64 + n;
      #pragma unroll
      for (int i = 0; i < 32; ++i) cb[i * 64] = acc[i];
    }
  } else {
    int tau = blockIdx.x - 128;
    float* PT = (float*)sm3;             // 16KB
    float* KT = (float*)(sm3 + 16384);   // 16KB
    for (int idx = t; idx < 4096; idx += 256) {
      PT[idx] = P[tau * 4096 + idx];
      KT[idx] = Kv[idx];
    }
    __syncthreads();
    int wn = t & 63, kq = t >> 6;
    f16* wrow = W16 + ((size_t)(tau * 64 + wn)) * 256 + kq * 64;
    if (kq == 0) {
      for (int k = 0; k < 64; ++k)
        wrow[k] = (f16)((k <= tau) ? KT[(tau - k) * 64 + wn] : 0.0f);
    } else if (kq == 2) {
      for (int m = 0; m < 64; ++m) {
        float p = PT[wn * 64 + m];
        f16 h = (f16)p;
        wrow[m] = (f16)(p - (float)h);
      }
    } else {
      for (int m = 0; m < 64; ++m) wrow[m] = (f16)PT[wn * 64 + m];
    }
  }
}

// ---------------- K4: 32-step scan, state in lanes, shfl matvec ----------------
__global__ __launch_bounds__(256) void k4_scan(
    const float* __restrict__ P, const float* __restrict__ c,
    f16* __restrict__ R16)
{
  int t = threadIdx.x;
  int wv = t >> 6, n = t & 63;
  int q = blockIdx.x * 4 + wv;
  const float* A64r = P + 63 * 4096 + n * 64;   // A^64 row n
  float ar[64];
  #pragma unroll
  for (int m = 0; m < 64; m += 4) {
    f32x4 v = *(const f32x4*)(A64r + m);
    ar[m] = v.x; ar[m + 1] = v.y; ar[m + 2] = v.z; ar[m + 3] = v.w;
  }
  float x = 0.f;
  #pragma unroll
  for (int j = 0; j < 32; ++j) {
    f16 hh = (f16)x;
    f16 ll = (f16)(x - (float)hh);
    f16* row = R16 + ((size_t)(j * 512 + q)) * 256;
    row[64 + n] = hh; row[128 + n] = hh; row[192 + n] = ll;
    float cj = c[(size_t)j * 32768 + (size_t)q * 64 + n];
    float a0 = 0.f, a1 = 0.f, a2 = 0.f, a3 = 0.f;
    #pragma unroll
    for (int m = 0; m < 64; m += 4) {
      a0 += ar[m + 0] * __shfl(x, m + 0);
      a1 += ar[m + 1] * __shfl(x, m + 1);
      a2 += ar[m + 2] * __shfl(x, m + 2);
      a3 += ar[m + 3] * __shfl(x, m + 3);
    }
    x = (a0 + a1) + (a2 + a3) + cj;
  }
}

// ---------------- K5: C[16384 x 4096] = R16 @ W16^T, staged coalesced epilogue ----------------
__global__ __launch_bounds__(256) void k5_gemm(
    const f16* __restrict__ R16, const f16* __restrict__ W16,
    float* __restrict__ out)
{
  __shared__ __align__(16) char smem[2 * 128 * 72 * 2];  // 36864 B
  f16 (*Asm)[72] = (f16 (*)[72])smem;
  f16 (*Bsm)[72] = (f16 (*)[72])(smem + 128 * 72 * 2);
  float (*stg)[66] = (float (*)[66])smem;                // 33792 B, aliased
  int wg = blockIdx.x;
  int swz = (wg & 7) * 512 + (wg >> 3);     // XCD-contiguous mt ranges
  int mt = swz >> 5, nt = swz & 31;
  int t = threadIdx.x, wave = t >> 6, lane = t & 63;
  int wr = wave >> 1, wc = wave & 1;
  int kg = lane >> 4, fr = lane & 15;
  f32x4 acc[4][4] = {};
  for (int ks = 0; ks < 4; ++ks) {
    #pragma unroll
    for (int ii = 0; ii < 4; ++ii) {
      int s = t + ii * 256;
      int row = s >> 3, sg = (s & 7) * 8;
      *(f16x8*)(&Asm[row][sg]) =
        *(const f16x8*)(R16 + ((size_t)(mt * 128 + row)) * 256 + ks * 64 + sg);
      *(f16x8*)(&Bsm[row][sg]) =
        *(const f16x8*)(W16 + ((size_t)(nt * 128 + row)) * 256 + ks * 64 + sg);
    }
    __syncthreads();
    #pragma unroll
    for (int kk = 0; kk < 2; ++kk) {
      f16x8 af[4], bf[4];
      #pragma unroll
      for (int i = 0; i < 4; ++i) {
        af[i] = *(const f16x8*)(&Asm[wr * 64 + i * 16 + fr][kk * 32 + kg * 8]);
        bf[i] = *(const f16x8*)(&Bsm[wc * 64 + i * 16 + fr][kk * 32 + kg * 8]);
      }
      #pragma unroll
      for (int mi = 0; mi < 4; ++mi)
        #pragma unroll
        for (int ni = 0; ni < 4; ++ni)
          acc[mi][ni] = __builtin_amdgcn_mfma_f32_16x16x32_f16(
              af[mi], bf[ni], acc[mi][ni], 0, 0, 0);
    }
    __syncthreads();
  }
  // epilogue: per tau-half, stage 128x64 f32 tile in LDS, write 32KB contiguous
  int j = mt >> 2, q0 = (mt & 3) * 128;
  #pragma unroll
  for (int half = 0; half < 2; ++half) {
    if (wc == half) {
      #pragma unroll
      for (int mi = 0; mi < 4; ++mi)
        #pragma unroll
        for (int ni = 0; ni < 4; ++ni)
          #pragma unroll
          for (int r = 0; r < 4; ++r)
            stg[wr * 64 + mi * 16 + kg * 4 + r][ni * 16 + fr] = acc[mi][ni][r];
    }
    __syncthreads();
    int tau_g = nt * 2 + half;
    float* obase = out + (size_t)j * 2097152 + (size_t)tau_g * 32768 + (size_t)q0 * 64;
    #pragma unroll
    for (int it = 0; it < 8; ++it) {
      int fi = it * 1024 + t * 4;
      int rr = fi >> 6, cc = fi & 63;
      *(f32x4*)(obase + fi) = *(const f32x4*)(&stg[rr][cc]);
    }
    __syncthreads();
  }
}

extern "C" void kernel_launch(void* const* d_in, const int* in_sizes, int n_in,
                              void* d_out, int out_size, void* d_ws, size_t ws_size,
                              hipStream_t stream)
{
  (void)in_sizes; (void)n_in; (void)out_size; (void)ws_size;
  const float* inp = (const float*)d_in[0];   // (2048, 8, 64) fp32
  const float* A   = (const float*)d_in[1];   // (64, 64) fp32
  const float* Bm  = (const float*)d_in[2];   // (64, 1) fp32
  float* out = (float*)d_out;                 // (2048, 8, 64, 64) fp32

  float* ws = (float*)d_ws;
  float* P  = ws;                             // 64*4096 f32   (1 MB)
  float* Kv = ws + 262144;                    // 64*64 f32     (16 KB)
  float* c  = ws + 266240;                    // 32*512*64 f32 (4 MB)
  f16*  W16 = (f16*)(ws + 1314816);           // 4096*256 f16  (2 MB)
  f16*  R16 = (f16*)((char*)d_ws + 7356416);  // 16384*256 f16 (8 MB)

  hipLaunchKernelGGL(k12_pow,  dim3(64),   dim3(1024), 0, stream, A, Bm, P, Kv);
  hipLaunchKernelGGL(k3_chunk, dim3(192),  dim3(256),  0, stream, inp, Kv, P, c, R16, W16);
  hipLaunchKernelGGL(k4_scan,  dim3(128),  dim3(256),  0, stream, P, c, R16);
  hipLaunchKernelGGL(k5_gemm,  dim3(4096), dim3(256),  0, stream, R16, W16, out);
}

// Round 3
// 150.342 us; speedup vs baseline: 1.3377x; 1.0984x over previous
//
#include <hip/hip_runtime.h>

// MemoryProjection: x_t = A x_{t-1} + in_t * Bd, out = all states (2048,8,64,64) fp32.
// Chunked: out[j*64+tau] = A^(tau+1) x0_j + sum_{k<=tau} (A^(tau-k) Bd) in[j*64+k]
// => one fp16 MFMA GEMM: C[m=(j,q)][nn=(tau,n)] = R16[m][:] . W16[nn][:], K=256
//    R16 = [in(64) | x0h(64) | x0h(64) | x0l(64)], W16 = [Kmat | Ph | Pl | Ph]
// kA: P[tau]=A^(tau+1) via A^(8a)*A^b; writes W16 Ph/Pl rows directly, Kv, A64
// kB: blocks 0..127 input transpose->R16[0:64); 128..191 W16 Kmat rows;
//     192..319 fused conv+scan (c_j on the fly via shfl, 32-step state recurrence)
// kC: 128x128 MFMA GEMM, reg-staged prefetch, NON-TEMPORAL output stores
//     (write-allocate of the 268MB output was evicting R16/W16 from L2)

typedef _Float16 f16;
typedef __attribute__((ext_vector_type(8))) _Float16 f16x8;
typedef __attribute__((ext_vector_type(4))) float f32x4;

// ---------------- kA: powers + W16 Ph/Pl + Kv + A64 ----------------
__global__ __launch_bounds__(1024) void kA_pow(
    const float* __restrict__ A, const float* __restrict__ Bm,
    float* __restrict__ A64, float* __restrict__ Kv, f16* __restrict__ W16)
{
  __shared__ float L1[64][68];
  __shared__ float Cur[64][68];
  __shared__ float Nxt[64][68];
  __shared__ float LbS[64][68];
  __shared__ float L8S[64][68];
  int tau = blockIdx.x;
  int e = tau + 1;
  int a = e >> 3, b = e & 7;
  int t = threadIdx.x;
  int n = t >> 4, m0 = (t & 15) * 4;

  for (int idx = t; idx < 4096; idx += 1024) {
    float v = A[idx];
    L1[idx >> 6][idx & 63] = v;
    Cur[idx >> 6][idx & 63] = v;
  }
  __syncthreads();

  auto mm = [&](float (*s1)[68], float (*s2)[68], float (*d)[68]) {
    float a0 = 0.f, a1 = 0.f, a2 = 0.f, a3 = 0.f;
    #pragma unroll 8
    for (int k = 0; k < 64; ++k) {
      float av = s1[n][k];
      f32x4 bv = *(const f32x4*)(&s2[k][m0]);
      a0 += av * bv.x; a1 += av * bv.y; a2 += av * bv.z; a3 += av * bv.w;
    }
    d[n][m0 + 0] = a0; d[n][m0 + 1] = a1;
    d[n][m0 + 2] = a2; d[n][m0 + 3] = a3;
    __syncthreads();
  };
  auto cpy = [&](float (*s)[68], float (*d)[68]) {
    for (int idx = t; idx < 4096; idx += 1024)
      d[idx >> 6][idx & 63] = s[idx >> 6][idx & 63];
    __syncthreads();
  };

  float (*cur)[68] = Cur, (*oth)[68] = Nxt;
  if (b == 1) cpy(cur, LbS);
  int loMax = (a >= 1) ? 8 : b;
  for (int i = 2; i <= loMax; ++i) {
    mm(cur, L1, oth);
    { float (*tmp)[68] = cur; cur = oth; oth = tmp; }
    if (i == b) cpy(cur, LbS);
    if (i == 8) cpy(cur, L8S);
  }

  float (*res)[68];
  if (a == 0) {
    res = LbS;
  } else {
    float (*d0)[68] = Cur, (*d1)[68] = Nxt;
    float (*h)[68] = L8S;
    for (int a2 = 2; a2 <= a; ++a2) {
      mm(h, L8S, d0);
      h = d0;
      { float (*tmp)[68] = d0; d0 = d1; d1 = tmp; }
    }
    if (b == 0) { res = h; }
    else        { mm(h, LbS, d0); res = d0; }
  }

  // W16 rows for this tau: [64..128)=Ph, [128..192)=Pl, [192..256)=Ph
  for (int idx = t; idx < 4096; idx += 1024) {
    int wn = idx >> 6, m = idx & 63;
    float p = res[wn][m];
    f16 h = (f16)p, l = (f16)(p - (float)h);
    f16* wrow = W16 + ((size_t)(tau * 64 + wn)) * 256;
    wrow[64 + m] = h; wrow[128 + m] = l; wrow[192 + m] = h;
  }
  if (tau == 63)
    for (int idx = t; idx < 4096; idx += 1024)
      A64[idx] = res[idx >> 6][idx & 63];
  if (t < 64) {
    float s = 0.f;
    #pragma unroll 8
    for (int m = 0; m < 64; ++m) s += res[t][m] * Bm[m];
    if (tau < 63) Kv[(tau + 1) * 64 + t] = s;
    else          Kv[t] = Bm[t];
  }
}

// ---------------- kB: transpose | Kmat | fused conv+scan ----------------
__global__ __launch_bounds__(256) void kB_prep(
    const float* __restrict__ inp, const float* __restrict__ Kv,
    const float* __restrict__ A64,
    f16* __restrict__ R16, f16* __restrict__ W16)
{
  __shared__ __align__(16) float sm[64 * 132];
  int t = threadIdx.x;
  int b = blockIdx.x;
  if (b < 128) {
    // input transpose: R16[(j*512+q)][k] = fp16(in[j*64+k][q])
    float (*tile)[132] = (float (*)[132])sm;
    int j = b >> 2, qb = (b & 3) * 128;
    {
      int k = t >> 2, sg = (t & 3) * 32;
      const float* src = inp + j * 32768 + k * 512 + qb + sg;
      #pragma unroll
      for (int i = 0; i < 32; i += 4)
        *(f32x4*)(&tile[k][sg + i]) = *(const f32x4*)(src + i);
    }
    __syncthreads();
    int q = t >> 1, kh = (t & 1) * 32;
    f16 tmp[32];
    #pragma unroll
    for (int kk = 0; kk < 32; ++kk)
      tmp[kk] = (f16)tile[kh + kk][q];
    f16* dst = R16 + ((size_t)(j * 512 + qb + q)) * 256 + kh;
    #pragma unroll
    for (int v = 0; v < 4; ++v)
      *(f16x8*)(dst + v * 8) = *(const f16x8*)(&tmp[v * 8]);
  } else if (b < 192) {
    // Kmat rows: W16[(tau*64+wn)][k] = (k<=tau) ? Kv[tau-k][wn] : 0
    int tau = b - 128;
    float* KT = sm;
    for (int idx = t; idx < 4096; idx += 256) KT[idx] = Kv[idx];
    __syncthreads();
    int wn = t & 63, kq = t >> 6;
    f16* wrow = W16 + ((size_t)(tau * 64 + wn)) * 256 + kq * 16;
    #pragma unroll
    for (int ki = 0; ki < 16; ++ki) {
      int k = kq * 16 + ki;
      wrow[ki] = (f16)((k <= tau) ? KT[(tau - k) * 64 + wn] : 0.0f);
    }
  } else {
    // fused conv+scan: one wave per q column
    int wv = t >> 6, L = t & 63;
    int q = (b - 192) * 4 + wv;
    float ar[64], kvr[64];
    #pragma unroll
    for (int m = 0; m < 64; m += 4) {
      f32x4 v4 = *(const f32x4*)(A64 + L * 64 + m);
      ar[m] = v4.x; ar[m + 1] = v4.y; ar[m + 2] = v4.z; ar[m + 3] = v4.w;
    }
    #pragma unroll
    for (int k = 0; k < 64; ++k) kvr[k] = Kv[(63 - k) * 64 + L];
    float x = 0.f;
    float v = inp[(size_t)L * 512 + q];
    for (int j = 0; j < 32; ++j) {
      float vn = (j < 31) ? inp[(size_t)((j + 1) * 64 + L) * 512 + q] : 0.f;
      f16 hh = (f16)x, ll = (f16)(x - (float)hh);
      f16* row = R16 + ((size_t)(j * 512 + q)) * 256;
      row[64 + L] = hh; row[128 + L] = hh; row[192 + L] = ll;
      float a0 = 0.f, a1 = 0.f, c0 = 0.f, c1 = 0.f;
      #pragma unroll
      for (int m = 0; m < 64; m += 2) {
        a0 += ar[m]     * __shfl(x, m);
        a1 += ar[m + 1] * __shfl(x, m + 1);
        c0 += kvr[m]    * __shfl(v, m);
        c1 += kvr[m + 1]* __shfl(v, m + 1);
      }
      x = (a0 + a1) + (c0 + c1);
      v = vn;
    }
  }
}

// ---------------- kC: C[16384 x 4096] = R16 @ W16^T, nt stores ----------------
__global__ __launch_bounds__(256) void kC_gemm(
    const f16* __restrict__ R16, const f16* __restrict__ W16,
    float* __restrict__ out)
{
  __shared__ __align__(16) char smem[2 * 128 * 72 * 2];  // 36864 B
  f16 (*Asm)[72] = (f16 (*)[72])smem;
  f16 (*Bsm)[72] = (f16 (*)[72])(smem + 128 * 72 * 2);
  float (*stg)[68] = (float (*)[68])smem;                // 34816 B, aliased
  int wg = blockIdx.x;
  int swz = (wg & 7) * 512 + (wg >> 3);     // XCD-contiguous mt ranges
  int mt = swz >> 5, nt = swz & 31;
  int t = threadIdx.x, wave = t >> 6, lane = t & 63;
  int wr = wave >> 1, wc = wave & 1;
  int kg = lane >> 4, fr = lane & 15;
  f32x4 acc[4][4] = {};
  f16x8 pa[4], pb[4];

  auto issue = [&](int ks) {
    #pragma unroll
    for (int ii = 0; ii < 4; ++ii) {
      int s = t + ii * 256;
      int row = s >> 3, sg = (s & 7) * 8;
      pa[ii] = *(const f16x8*)(R16 + ((size_t)(mt * 128 + row)) * 256 + ks * 64 + sg);
      pb[ii] = *(const f16x8*)(W16 + ((size_t)(nt * 128 + row)) * 256 + ks * 64 + sg);
    }
  };

  issue(0);
  for (int ks = 0; ks < 4; ++ks) {
    #pragma unroll
    for (int ii = 0; ii < 4; ++ii) {
      int s = t + ii * 256;
      int row = s >> 3, sg = (s & 7) * 8;
      *(f16x8*)(&Asm[row][sg]) = pa[ii];
      *(f16x8*)(&Bsm[row][sg]) = pb[ii];
    }
    if (ks < 3) issue(ks + 1);     // next-tile loads in flight during MFMA
    __syncthreads();
    #pragma unroll
    for (int kk = 0; kk < 2; ++kk) {
      f16x8 af[4], bf[4];
      #pragma unroll
      for (int i = 0; i < 4; ++i) {
        af[i] = *(const f16x8*)(&Asm[wr * 64 + i * 16 + fr][kk * 32 + kg * 8]);
        bf[i] = *(const f16x8*)(&Bsm[wc * 64 + i * 16 + fr][kk * 32 + kg * 8]);
      }
      #pragma unroll
      for (int mi = 0; mi < 4; ++mi)
        #pragma unroll
        for (int ni = 0; ni < 4; ++ni)
          acc[mi][ni] = __builtin_amdgcn_mfma_f32_16x16x32_f16(
              af[mi], bf[ni], acc[mi][ni], 0, 0, 0);
    }
    __syncthreads();
  }
  // epilogue: per tau-half, stage 128x64 f32 tile in LDS, nt-write 32KB contiguous
  int j = mt >> 2, q0 = (mt & 3) * 128;
  #pragma unroll
  for (int half = 0; half < 2; ++half) {
    if (wc == half) {
      #pragma unroll
      for (int mi = 0; mi < 4; ++mi)
        #pragma unroll
        for (int ni = 0; ni < 4; ++ni)
          #pragma unroll
          for (int r = 0; r < 4; ++r)
            stg[wr * 64 + mi * 16 + kg * 4 + r][ni * 16 + fr] = acc[mi][ni][r];
    }
    __syncthreads();
    int tau_g = nt * 2 + half;
    float* obase = out + (size_t)j * 2097152 + (size_t)tau_g * 32768 + (size_t)q0 * 64;
    #pragma unroll
    for (int it = 0; it < 8; ++it) {
      int fi = it * 1024 + t * 4;
      int rr = fi >> 6, cc = fi & 63;
      __builtin_nontemporal_store(*(const f32x4*)(&stg[rr][cc]),
                                  (f32x4*)(obase + fi));
    }
    __syncthreads();
  }
}

extern "C" void kernel_launch(void* const* d_in, const int* in_sizes, int n_in,
                              void* d_out, int out_size, void* d_ws, size_t ws_size,
                              hipStream_t stream)
{
  (void)in_sizes; (void)n_in; (void)out_size; (void)ws_size;
  const float* inp = (const float*)d_in[0];   // (2048, 8, 64) fp32
  const float* A   = (const float*)d_in[1];   // (64, 64) fp32
  const float* Bm  = (const float*)d_in[2];   // (64, 1) fp32
  float* out = (float*)d_out;                 // (2048, 8, 64, 64) fp32

  float* ws = (float*)d_ws;
  float* A64 = ws;                            // 4096 f32   (16 KB)
  float* Kv  = ws + 4096;                     // 4096 f32   (16 KB)
  f16*  W16  = (f16*)(ws + 8192);             // 4096*256 f16 (2 MB)
  f16*  R16  = (f16*)((char*)d_ws + 2129920); // 16384*256 f16 (8 MB)

  hipLaunchKernelGGL(kA_pow,  dim3(64),   dim3(1024), 0, stream, A, Bm, A64, Kv, W16);
  hipLaunchKernelGGL(kB_prep, dim3(320),  dim3(256),  0, stream, inp, Kv, A64, R16, W16);
  hipLaunchKernelGGL(kC_gemm, dim3(4096), dim3(256),  0, stream, R16, W16, out);
}

// Round 5
// 124.598 us; speedup vs baseline: 1.6141x; 1.2066x over previous
//
#include <hip/hip_runtime.h>

// MemoryProjection: x_t = A x_{t-1} + in_t * Bd, out = all states (2048,8,64,64) fp32.
// Chunked: out[j*64+tau] = A^(tau+1) x0_j + sum_{k<=tau} (A^(tau-k) Bd) in[j*64+k]
// => one fp16 MFMA GEMM: C[m=(j,q)][nn=(tau,n)] = R16[m][:] . W16[nn][:], K=256
//    R16 = [in(64) | x0h(64) | x0h(64) | x0l(64)], W16 = [Kmat | Ph | Pl | Ph]
// kA: P[tau]=A^(tau+1) chains via f16 h/l-compensated MFMA matmuls
//     (lo chain transposed: Y_{i+1}=mfma(Y_i,A); hi chain: H_{a+1}=mfma(H_a,Y8);
//      final mfma(H_a,Y_b) -- only ONE explicit transpose per block).
//     NOTE: no LDS-pointer arrays with init lists (addrspacecast static-init
//     compile error) -- named ping/pong pointers swapped at runtime instead.
// kB: blocks 0..127 input transpose->R16; 128..191 W16 Kmat; 192..319 fused conv+scan
// kC: 128x128 MFMA GEMM, reg-staged prefetch, non-temporal output stores

typedef _Float16 f16;
typedef __attribute__((ext_vector_type(8))) _Float16 f16x8;
typedef __attribute__((ext_vector_type(4))) float f32x4;

// ---------------- kA: powers via h/l MFMA + W16 Ph/Pl + Kv + A64 ----------------
__global__ __launch_bounds__(1024) void kA_pow(
    const float* __restrict__ A, const float* __restrict__ Bm,
    float* __restrict__ A64, float* __restrict__ Kv, f16* __restrict__ W16)
{
  __shared__ __align__(16) f16 Ah[64][72],  Al[64][72];   // A row-major h/l
  __shared__ __align__(16) f16 B0h[64][72], B0l[64][72];  // ping
  __shared__ __align__(16) f16 B1h[64][72], B1l[64][72];  // pong
  __shared__ __align__(16) f16 Y8h[64][72], Y8l[64][72];  // (A^8)^T capture
  __shared__ __align__(16) f16 Ybh[64][72], Ybl[64][72];  // (A^b)^T capture

  int tau = blockIdx.x;
  int e = tau + 1;
  int a = e >> 3, b = e & 7;
  int t = threadIdx.x;
  int wave = t >> 6, lane = t & 63;
  int tn = wave >> 2, tm = wave & 3;       // 4x4 grid of 16x16 tiles
  int kg = lane >> 4, fr = lane & 15;

  // D = P * Q^T (both row-major [row][k]), h/l compensated; D split to h/l.
  auto mm = [&](f16 (*Ph)[72], f16 (*Pl)[72], f16 (*Qh)[72], f16 (*Ql)[72],
                f16 (*Dh)[72], f16 (*Dl)[72]) {
    f32x4 acc = {};
    #pragma unroll
    for (int kk = 0; kk < 2; ++kk) {
      f16x8 ah = *(const f16x8*)&Ph[tn * 16 + fr][kk * 32 + kg * 8];
      f16x8 al = *(const f16x8*)&Pl[tn * 16 + fr][kk * 32 + kg * 8];
      f16x8 bh = *(const f16x8*)&Qh[tm * 16 + fr][kk * 32 + kg * 8];
      f16x8 bl = *(const f16x8*)&Ql[tm * 16 + fr][kk * 32 + kg * 8];
      acc = __builtin_amdgcn_mfma_f32_16x16x32_f16(ah, bh, acc, 0, 0, 0);
      acc = __builtin_amdgcn_mfma_f32_16x16x32_f16(ah, bl, acc, 0, 0, 0);
      acc = __builtin_amdgcn_mfma_f32_16x16x32_f16(al, bh, acc, 0, 0, 0);
    }
    #pragma unroll
    for (int r = 0; r < 4; ++r) {
      float v = acc[r];
      f16 h = (f16)v, l = (f16)(v - (float)h);
      Dh[tn * 16 + kg * 4 + r][tm * 16 + fr] = h;
      Dl[tn * 16 + kg * 4 + r][tm * 16 + fr] = l;
    }
    __syncthreads();
  };
  auto cpy2 = [&](f16 (*Sh)[72], f16 (*Sl)[72], f16 (*Dh)[72], f16 (*Dl)[72]) {
    const unsigned* sh = (const unsigned*)Sh; unsigned* dh = (unsigned*)Dh;
    const unsigned* sl = (const unsigned*)Sl; unsigned* dl = (unsigned*)Dl;
    for (int idx = t; idx < 2304; idx += 1024) { dh[idx] = sh[idx]; dl[idx] = sl[idx]; }
  };

  // init: Ah/Al = h/l(A) row-major; ping = h/l(A^T) = Y_1
  for (int idx = t; idx < 4096; idx += 1024) {
    float v = A[idx];
    int r = idx >> 6, c2 = idx & 63;
    f16 h = (f16)v, l = (f16)(v - (float)h);
    Ah[r][c2] = h;  Al[r][c2] = l;
    B0h[c2][r] = h; B0l[c2][r] = l;
  }
  __syncthreads();

  f16 (*curH)[72] = B0h; f16 (*curL)[72] = B0l;
  f16 (*othH)[72] = B1h; f16 (*othL)[72] = B1l;
  auto swp = [&]() {
    f16 (*tH)[72] = curH; curH = othH; othH = tH;
    f16 (*tL)[72] = curL; curL = othL; othL = tL;
  };

  if (b == 1) cpy2(curH, curL, Ybh, Ybl);

  // lo chain (transposed space): Y_{i+1} = mfma(Y_i, A_rm)
  int loMax = (a >= 1) ? 8 : b;
  for (int i = 2; i <= loMax; ++i) {
    mm(curH, curL, Ah, Al, othH, othL);
    swp();
    if (i == b) cpy2(curH, curL, Ybh, Ybl);
    if (i == 8) cpy2(curH, curL, Y8h, Y8l);
  }

  f16 (*Rh)[72]; f16 (*Rl)[72]; bool tr;
  if (a == 0) {
    Rh = curH; Rl = curL; tr = true;                // result = Y_b^T
  } else {
    // H_1 = A^8 = transpose(Y_8) (Y_8 currently in cur)
    for (int idx = t; idx < 4096; idx += 1024) {
      int i = idx >> 6, j = idx & 63;
      othH[i][j] = curH[j][i];
      othL[i][j] = curL[j][i];
    }
    swp();
    __syncthreads();
    for (int a2 = 2; a2 <= a; ++a2) {               // H_{a+1} = mfma(H_a, Y8)
      mm(curH, curL, Y8h, Y8l, othH, othL);
      swp();
    }
    if (b >= 1) {                                   // P = mfma(H_a, Y_b)
      mm(curH, curL, Ybh, Ybl, othH, othL);
      swp();
    }
    Rh = curH; Rl = curL; tr = false;
  }

  // epilogue: W16 rows [64..128)=Ph, [128..192)=Pl, [192..256)=Ph; A64; Kv
  for (int idx = t; idx < 4096; idx += 1024) {
    int wn = idx >> 6, m = idx & 63;
    f16 h = tr ? Rh[m][wn] : Rh[wn][m];
    f16 l = tr ? Rl[m][wn] : Rl[wn][m];
    f16* wrow = W16 + ((size_t)(tau * 64 + wn)) * 256;
    wrow[64 + m] = h; wrow[128 + m] = l; wrow[192 + m] = h;
    if (tau == 63) A64[idx] = (float)h + (float)l;
  }
  if (t < 64) {
    float s = 0.f;
    #pragma unroll 8
    for (int m = 0; m < 64; ++m) {
      float pv = tr ? ((float)Rh[m][t] + (float)Rl[m][t])
                    : ((float)Rh[t][m] + (float)Rl[t][m]);
      s += pv * Bm[m];
    }
    if (tau < 63) Kv[(tau + 1) * 64 + t] = s;
    else          Kv[t] = Bm[t];
  }
}

// ---------------- kB: transpose | Kmat | fused conv+scan ----------------
__global__ __launch_bounds__(256) void kB_prep(
    const float* __restrict__ inp, const float* __restrict__ Kv,
    const float* __restrict__ A64,
    f16* __restrict__ R16, f16* __restrict__ W16)
{
  __shared__ __align__(16) float sm[64 * 132];
  int t = threadIdx.x;
  int b = blockIdx.x;
  if (b < 128) {
    // input transpose: R16[(j*512+q)][k] = fp16(in[j*64+k][q])
    float (*tile)[132] = (float (*)[132])sm;
    int j = b >> 2, qb = (b & 3) * 128;
    {
      int k = t >> 2, sg = (t & 3) * 32;
      const float* src = inp + j * 32768 + k * 512 + qb + sg;
      #pragma unroll
      for (int i = 0; i < 32; i += 4)
        *(f32x4*)(&tile[k][sg + i]) = *(const f32x4*)(src + i);
    }
    __syncthreads();
    int q = t >> 1, kh = (t & 1) * 32;
    f16 tmp[32];
    #pragma unroll
    for (int kk = 0; kk < 32; ++kk)
      tmp[kk] = (f16)tile[kh + kk][q];
    f16* dst = R16 + ((size_t)(j * 512 + qb + q)) * 256 + kh;
    #pragma unroll
    for (int v = 0; v < 4; ++v)
      *(f16x8*)(dst + v * 8) = *(const f16x8*)(&tmp[v * 8]);
  } else if (b < 192) {
    // Kmat rows: W16[(tau*64+wn)][k] = (k<=tau) ? Kv[tau-k][wn] : 0
    int tau = b - 128;
    float* KT = sm;
    for (int idx = t; idx < 4096; idx += 256) KT[idx] = Kv[idx];
    __syncthreads();
    int wn = t & 63, kq = t >> 6;
    f16* wrow = W16 + ((size_t)(tau * 64 + wn)) * 256 + kq * 16;
    #pragma unroll
    for (int ki = 0; ki < 16; ++ki) {
      int k = kq * 16 + ki;
      wrow[ki] = (f16)((k <= tau) ? KT[(tau - k) * 64 + wn] : 0.0f);
    }
  } else {
    // fused conv+scan: one wave per q column
    int wv = t >> 6, L = t & 63;
    int q = (b - 192) * 4 + wv;
    float ar[64], kvr[64];
    #pragma unroll
    for (int m = 0; m < 64; m += 4) {
      f32x4 v4 = *(const f32x4*)(A64 + L * 64 + m);
      ar[m] = v4.x; ar[m + 1] = v4.y; ar[m + 2] = v4.z; ar[m + 3] = v4.w;
    }
    #pragma unroll
    for (int k = 0; k < 64; ++k) kvr[k] = Kv[(63 - k) * 64 + L];
    float x = 0.f;
    float v = inp[(size_t)L * 512 + q];
    for (int j = 0; j < 32; ++j) {
      float vn = (j < 31) ? inp[(size_t)((j + 1) * 64 + L) * 512 + q] : 0.f;
      f16 hh = (f16)x, ll = (f16)(x - (float)hh);
      f16* row = R16 + ((size_t)(j * 512 + q)) * 256;
      row[64 + L] = hh; row[128 + L] = hh; row[192 + L] = ll;
      float a0 = 0.f, a1 = 0.f, c0 = 0.f, c1 = 0.f;
      #pragma unroll
      for (int m = 0; m < 64; m += 2) {
        a0 += ar[m]     * __shfl(x, m);
        a1 += ar[m + 1] * __shfl(x, m + 1);
        c0 += kvr[m]    * __shfl(v, m);
        c1 += kvr[m + 1]* __shfl(v, m + 1);
      }
      x = (a0 + a1) + (c0 + c1);
      v = vn;
    }
  }
}

// ---------------- kC: C[16384 x 4096] = R16 @ W16^T, nt stores ----------------
__global__ __launch_bounds__(256) void kC_gemm(
    const f16* __restrict__ R16, const f16* __restrict__ W16,
    float* __restrict__ out)
{
  __shared__ __align__(16) char smem[2 * 128 * 72 * 2];  // 36864 B
  f16 (*Asm)[72] = (f16 (*)[72])smem;
  f16 (*Bsm)[72] = (f16 (*)[72])(smem + 128 * 72 * 2);
  float (*stg)[68] = (float (*)[68])smem;                // 34816 B, aliased
  int wg = blockIdx.x;
  int swz = (wg & 7) * 512 + (wg >> 3);     // XCD-contiguous mt ranges
  int mt = swz >> 5, nt = swz & 31;
  int t = threadIdx.x, wave = t >> 6, lane = t & 63;
  int wr = wave >> 1, wc = wave & 1;
  int kg = lane >> 4, fr = lane & 15;
  f32x4 acc[4][4] = {};
  f16x8 pa[4], pb[4];

  auto issue = [&](int ks) {
    #pragma unroll
    for (int ii = 0; ii < 4; ++ii) {
      int s = t + ii * 256;
      int row = s >> 3, sg = (s & 7) * 8;
      pa[ii] = *(const f16x8*)(R16 + ((size_t)(mt * 128 + row)) * 256 + ks * 64 + sg);
      pb[ii] = *(const f16x8*)(W16 + ((size_t)(nt * 128 + row)) * 256 + ks * 64 + sg);
    }
  };

  issue(0);
  for (int ks = 0; ks < 4; ++ks) {
    #pragma unroll
    for (int ii = 0; ii < 4; ++ii) {
      int s = t + ii * 256;
      int row = s >> 3, sg = (s & 7) * 8;
      *(f16x8*)(&Asm[row][sg]) = pa[ii];
      *(f16x8*)(&Bsm[row][sg]) = pb[ii];
    }
    if (ks < 3) issue(ks + 1);     // next-tile loads in flight during MFMA
    __syncthreads();
    #pragma unroll
    for (int kk = 0; kk < 2; ++kk) {
      f16x8 af[4], bf[4];
      #pragma unroll
      for (int i = 0; i < 4; ++i) {
        af[i] = *(const f16x8*)(&Asm[wr * 64 + i * 16 + fr][kk * 32 + kg * 8]);
        bf[i] = *(const f16x8*)(&Bsm[wc * 64 + i * 16 + fr][kk * 32 + kg * 8]);
      }
      #pragma unroll
      for (int mi = 0; mi < 4; ++mi)
        #pragma unroll
        for (int ni = 0; ni < 4; ++ni)
          acc[mi][ni] = __builtin_amdgcn_mfma_f32_16x16x32_f16(
              af[mi], bf[ni], acc[mi][ni], 0, 0, 0);
    }
    __syncthreads();
  }
  // epilogue: per tau-half, stage 128x64 f32 tile in LDS, nt-write 32KB contiguous
  int j = mt >> 2, q0 = (mt & 3) * 128;
  #pragma unroll
  for (int half = 0; half < 2; ++half) {
    if (wc == half) {
      #pragma unroll
      for (int mi = 0; mi < 4; ++mi)
        #pragma unroll
        for (int ni = 0; ni < 4; ++ni)
          #pragma unroll
          for (int r = 0; r < 4; ++r)
            stg[wr * 64 + mi * 16 + kg * 4 + r][ni * 16 + fr] = acc[mi][ni][r];
    }
    __syncthreads();
    int tau_g = nt * 2 + half;
    float* obase = out + (size_t)j * 2097152 + (size_t)tau_g * 32768 + (size_t)q0 * 64;
    #pragma unroll
    for (int it = 0; it < 8; ++it) {
      int fi = it * 1024 + t * 4;
      int rr = fi >> 6, cc = fi & 63;
      __builtin_nontemporal_store(*(const f32x4*)(&stg[rr][cc]),
                                  (f32x4*)(obase + fi));
    }
    __syncthreads();
  }
}

extern "C" void kernel_launch(void* const* d_in, const int* in_sizes, int n_in,
                              void* d_out, int out_size, void* d_ws, size_t ws_size,
                              hipStream_t stream)
{
  (void)in_sizes; (void)n_in; (void)out_size; (void)ws_size;
  const float* inp = (const float*)d_in[0];   // (2048, 8, 64) fp32
  const float* A   = (const float*)d_in[1];   // (64, 64) fp32
  const float* Bm  = (const float*)d_in[2];   // (64, 1) fp32
  float* out = (float*)d_out;                 // (2048, 8, 64, 64) fp32

  float* ws = (float*)d_ws;
  float* A64 = ws;                            // 4096 f32   (16 KB)
  float* Kv  = ws + 4096;                     // 4096 f32   (16 KB)
  f16*  W16  = (f16*)(ws + 8192);             // 4096*256 f16 (2 MB)
  f16*  R16  = (f16*)((char*)d_ws + 2129920); // 16384*256 f16 (8 MB)

  hipLaunchKernelGGL(kA_pow,  dim3(64),   dim3(1024), 0, stream, A, Bm, A64, Kv, W16);
  hipLaunchKernelGGL(kB_prep, dim3(320),  dim3(256),  0, stream, inp, Kv, A64, R16, W16);
  hipLaunchKernelGGL(kC_gemm, dim3(4096), dim3(256),  0, stream, R16, W16, out);
}